// Round 6
// baseline (119.416 us; speedup 1.0000x reference)
//
#include <hip/hip_runtime.h>

#define B_ 2048
#define T_ 256
#define F_ 64
#define EMB_ 16
#define UNITS_ 32
#define L2E 1.44269504f

typedef __attribute__((ext_vector_type(8))) short bf16x8;
typedef __attribute__((ext_vector_type(4))) float f32x4;

__device__ __forceinline__ unsigned short f2bf(float f) {  // RNE float->bf16
    unsigned u = __float_as_uint(f);
    return (unsigned short)((u + 0x7FFFu + ((u >> 16) & 1u)) >> 16);
}
__device__ __forceinline__ float fast_sigmoid(float x) {
    return __builtin_amdgcn_rcpf(1.0f + __builtin_amdgcn_exp2f(-L2E * x));
}

// ---------------- Kernel 1: embedding via MFMA (unchanged, ~HBM-bound) ------
__global__ __launch_bounds__(64) void embed_mfma(
    const float* __restrict__ x, const float* __restrict__ Wemb,
    const float* __restrict__ bemb, unsigned int* __restrict__ e_ws)
{
    __shared__ unsigned short slab[2][16][72];

    const int lane = threadIdx.x;
    const int g = lane >> 4, c = lane & 15;
    const int tile = blockIdx.x >> 5;
    const int t0 = (blockIdx.x & 31) * 8;

    bf16x8 A1, A2;
    #pragma unroll
    for (int j = 0; j < 4; ++j) {
        A1[j]     = (short)f2bf(Wemb[(4 * g + j) * EMB_ + c]);
        A1[j + 4] = (short)f2bf(Wemb[(16 + 4 * g + j) * EMB_ + c]);
        A2[j]     = (short)f2bf(Wemb[(32 + 4 * g + j) * EMB_ + c]);
        A2[j + 4] = (short)f2bf(Wemb[(48 + 4 * g + j) * EMB_ + c]);
    }
    f32x4 bc;
    #pragma unroll
    for (int r = 0; r < 4; ++r) bc[r] = bemb[4 * g + r];

    const int sr = lane >> 2, sc = lane & 3;
    const float* xs = x + (size_t)(tile * 16 + sr) * T_ * F_ + sc * 16;

    float4 rld[4], nld[4];
    {
        const float4* p = (const float4*)(xs + (size_t)t0 * F_);
        rld[0] = p[0]; rld[1] = p[1]; rld[2] = p[2]; rld[3] = p[3];
    }

    #pragma unroll
    for (int i = 0; i < 9; ++i) {
        if (i < 7) {
            const float4* p = (const float4*)(xs + (size_t)(t0 + i + 1) * F_);
            nld[0] = p[0]; nld[1] = p[1]; nld[2] = p[2]; nld[3] = p[3];
        }
        if (i < 8) {
            const float* f = (const float*)rld;
            unsigned u[8];
            #pragma unroll
            for (int k = 0; k < 8; ++k)
                u[k] = (unsigned)f2bf(f[2 * k]) | ((unsigned)f2bf(f[2 * k + 1]) << 16);
            uint4* d = (uint4*)&slab[i & 1][sr][sc * 16];
            d[0] = make_uint4(u[0], u[1], u[2], u[3]);
            d[1] = make_uint4(u[4], u[5], u[6], u[7]);
        }
        if (i > 0) {
            const unsigned short* row = &slab[(i - 1) & 1][c][0];
            ushort4 l1 = *(const ushort4*)(row + 4 * g);
            ushort4 h1 = *(const ushort4*)(row + 16 + 4 * g);
            ushort4 l2 = *(const ushort4*)(row + 32 + 4 * g);
            ushort4 h2 = *(const ushort4*)(row + 48 + 4 * g);
            bf16x8 B1 = {(short)l1.x, (short)l1.y, (short)l1.z, (short)l1.w,
                         (short)h1.x, (short)h1.y, (short)h1.z, (short)h1.w};
            bf16x8 B2 = {(short)l2.x, (short)l2.y, (short)l2.z, (short)l2.w,
                         (short)h2.x, (short)h2.y, (short)h2.z, (short)h2.w};
            f32x4 acc = __builtin_amdgcn_mfma_f32_16x16x32_bf16(A1, B1, bc, 0, 0, 0);
            acc = __builtin_amdgcn_mfma_f32_16x16x32_bf16(A2, B2, acc, 0, 0, 0);
            unsigned u0 = (unsigned)f2bf(fast_sigmoid(acc[0])) |
                          ((unsigned)f2bf(fast_sigmoid(acc[1])) << 16);
            unsigned u1 = (unsigned)f2bf(fast_sigmoid(acc[2])) |
                          ((unsigned)f2bf(fast_sigmoid(acc[3])) << 16);
            size_t idx = (((size_t)tile * T_ + (t0 + i - 1)) * 64 + lane) * 2;
            *(uint2*)(e_ws + idx) = make_uint2(u0, u1);
        }
        #pragma unroll
        for (int k = 0; k < 4; ++k) rld[k] = nld[k];
    }
}

// ---------------- Kernel 2: LSTM recurrence, 2 chains per wave ---------------
// 64 WGs x 4 waves (1 wave/SIMD). Each WG: TWO batch tiles (chains A,B).
// Wave w owns units [8w,8w+8) as 2 M-tiles per chain (same as r5). The two
// chains are data-independent -> chain B's issue fills chain A's
// exchange/MFMA/cell latency within the wave. One lgkm-only barrier per step.
__global__ __launch_bounds__(256) void lstm_rec(
    const float* __restrict__ Wf, const float* __restrict__ bfv,
    const float* __restrict__ Wi, const float* __restrict__ biv,
    const float* __restrict__ Wc, const float* __restrict__ bcv,
    const float* __restrict__ Wo, const float* __restrict__ bov,
    const float* __restrict__ Wout, const float* __restrict__ bout,
    const unsigned int* __restrict__ e_ws, float* __restrict__ out)
{
    __shared__ unsigned short hx[2][2][16][36];  // [chain][buf][batch][unit]
    __shared__ float pred[2][4][16];

    const int tid = threadIdx.x;
    const int w = tid >> 6;
    const int lane = tid & 63;
    const int g = lane >> 4, m15 = lane & 15;

    const int gate = m15 & 3;
    const float* Wsel = (gate == 0) ? Wf : (gate == 1) ? Wi : (gate == 2) ? Wc : Wo;
    const float ascale = (gate == 2) ? (-2.0f * L2E) : (-L2E);
    const int uAb = 8 * w + 2 * (m15 >> 2);

    bf16x8 Ah[2], Ae[2];
    #pragma unroll
    for (int tau = 0; tau < 2; ++tau) {
        const int uA = uAb + tau;
        #pragma unroll
        for (int j = 0; j < 4; ++j) {
            Ah[tau][j]     = (short)f2bf(ascale * Wsel[(4 * g + j) * UNITS_ + uA]);
            Ah[tau][j + 4] = (short)f2bf(ascale * Wsel[(16 + 4 * g + j) * UNITS_ + uA]);
            Ae[tau][j]     = (short)f2bf(ascale * Wsel[(32 + 4 * g + j) * UNITS_ + uA]);
            Ae[tau][j + 4] = 0;
        }
    }
    f32x4 bias[2];
    #pragma unroll
    for (int tau = 0; tau < 2; ++tau) {
        const int u = 8 * w + 2 * g + tau;
        bias[tau][0] = -L2E * bfv[u];
        bias[tau][1] = -L2E * biv[u];
        bias[tau][2] = -2.0f * L2E * bcv[u];
        bias[tau][3] = -L2E * bov[u];
    }

    const int btA = blockIdx.x * 2, btB = btA + 1;
    const uint2* epA = (const uint2*)e_ws + (size_t)btA * T_ * 64 + lane;
    const uint2* epB = (const uint2*)e_ws + (size_t)btB * T_ * 64 + lane;
    uint2 erA[4], erB[4];
    #pragma unroll
    for (int s = 0; s < 4; ++s) {
        erA[s] = epA[(size_t)s * 64];
        erB[s] = epB[(size_t)s * 64];
    }

    for (int i = tid; i < 2 * 2 * 16 * 36 / 2; i += 256) ((unsigned*)hx)[i] = 0;
    __syncthreads();

    float cA0 = 0.f, cA1 = 0.f, hfA0 = 0.f, hfA1 = 0.f;
    float cB0 = 0.f, cB1 = 0.f, hfB0 = 0.f, hfB1 = 0.f;

    auto cell = [&](const f32x4& acc, float& cst, float& hf) {
        float Ef = __builtin_amdgcn_exp2f(acc[0]);
        float Ei = __builtin_amdgcn_exp2f(acc[1]);
        float Ec = __builtin_amdgcn_exp2f(acc[2]);
        float Eo = __builtin_amdgcn_exp2f(acc[3]);
        float Pf = 1.f + Ef, Pi = 1.f + Ei, Pc = 1.f + Ec, Po = 1.f + Eo;
        float Mc = 1.f - Ec;
        float t1 = Pi * Pc;
        float num = fmaf(cst, t1, Pf * Mc);
        float den = Pf * t1;
        float cn = num * __builtin_amdgcn_rcpf(den);
        cst = cn;
        float Eh = __builtin_amdgcn_exp2f(cn * (-2.0f * L2E));
        float Mh = 1.f - Eh;
        float d2 = (1.f + Eh) * Po;
        hf = Mh * __builtin_amdgcn_rcpf(d2);
    };
    auto mkBe = [](uint2 ev) -> bf16x8 {
        return bf16x8{(short)(ev.x & 0xffff), (short)(ev.x >> 16),
                      (short)(ev.y & 0xffff), (short)(ev.y >> 16), 0, 0, 0, 0};
    };

    f32x4 FeA0, FeA1, FeB0, FeB1;
    {
        bf16x8 BeA = mkBe(erA[0]), BeB = mkBe(erB[0]);
        FeA0 = __builtin_amdgcn_mfma_f32_16x16x32_bf16(Ae[0], BeA, bias[0], 0, 0, 0);
        FeA1 = __builtin_amdgcn_mfma_f32_16x16x32_bf16(Ae[1], BeA, bias[1], 0, 0, 0);
        FeB0 = __builtin_amdgcn_mfma_f32_16x16x32_bf16(Ae[0], BeB, bias[0], 0, 0, 0);
        FeB1 = __builtin_amdgcn_mfma_f32_16x16x32_bf16(Ae[1], BeB, bias[1], 0, 0, 0);
    }

    #pragma unroll 1
    for (int t = 0; t < T_; t += 4) {
        #pragma unroll
        for (int s = 0; s < 4; ++s) {
            const int u = t + s;
            // both chains' h-reads issued together
            const unsigned short* hrA = &hx[0][u & 1][m15][0];
            const unsigned short* hrB = &hx[1][u & 1][m15][0];
            ushort4 alo = *(const ushort4*)(hrA + 4 * g);
            ushort4 ahi = *(const ushort4*)(hrA + 16 + 4 * g);
            ushort4 blo = *(const ushort4*)(hrB + 4 * g);
            ushort4 bhi = *(const ushort4*)(hrB + 16 + 4 * g);
            bf16x8 BhA = {(short)alo.x, (short)alo.y, (short)alo.z, (short)alo.w,
                          (short)ahi.x, (short)ahi.y, (short)ahi.z, (short)ahi.w};
            bf16x8 BhB = {(short)blo.x, (short)blo.y, (short)blo.z, (short)blo.w,
                          (short)bhi.x, (short)bhi.y, (short)bhi.z, (short)bhi.w};
            f32x4 aA0 = __builtin_amdgcn_mfma_f32_16x16x32_bf16(Ah[0], BhA, FeA0, 0, 0, 0);
            f32x4 aA1 = __builtin_amdgcn_mfma_f32_16x16x32_bf16(Ah[1], BhA, FeA1, 0, 0, 0);
            f32x4 aB0 = __builtin_amdgcn_mfma_f32_16x16x32_bf16(Ah[0], BhB, FeB0, 0, 0, 0);
            f32x4 aB1 = __builtin_amdgcn_mfma_f32_16x16x32_bf16(Ah[1], BhB, FeB1, 0, 0, 0);

            // next-step Fe (h-independent), refill prefetch ring
            int tn = (u + 4 < T_) ? u + 4 : T_ - 1;
            bf16x8 BeA = mkBe(erA[(s + 1) & 3]);
            bf16x8 BeB = mkBe(erB[(s + 1) & 3]);
            erA[s] = epA[(size_t)tn * 64];
            erB[s] = epB[(size_t)tn * 64];
            FeA0 = __builtin_amdgcn_mfma_f32_16x16x32_bf16(Ae[0], BeA, bias[0], 0, 0, 0);
            FeA1 = __builtin_amdgcn_mfma_f32_16x16x32_bf16(Ae[1], BeA, bias[1], 0, 0, 0);
            FeB0 = __builtin_amdgcn_mfma_f32_16x16x32_bf16(Ae[0], BeB, bias[0], 0, 0, 0);
            FeB1 = __builtin_amdgcn_mfma_f32_16x16x32_bf16(Ae[1], BeB, bias[1], 0, 0, 0);

            cell(aA0, cA0, hfA0);
            cell(aA1, cA1, hfA1);
            cell(aB0, cB0, hfB0);
            cell(aB1, cB1, hfB1);
            unsigned pkA, pkB;
            asm("v_cvt_pk_bf16_f32 %0, %1, %2" : "=v"(pkA) : "v"(hfA0), "v"(hfA1));
            asm("v_cvt_pk_bf16_f32 %0, %1, %2" : "=v"(pkB) : "v"(hfB0), "v"(hfB1));
            *(unsigned*)&hx[0][(u + 1) & 1][m15][8 * w + 2 * g] = pkA;
            *(unsigned*)&hx[1][(u + 1) & 1][m15][8 * w + 2 * g] = pkB;

            // lgkm-only barrier: global e-prefetch stays in flight
            asm volatile("s_waitcnt lgkmcnt(0)\n\ts_barrier" ::: "memory");
        }
    }

    float pA = hfA0 * Wout[8 * w + 2 * g] + hfA1 * Wout[8 * w + 2 * g + 1];
    float pB = hfB0 * Wout[8 * w + 2 * g] + hfB1 * Wout[8 * w + 2 * g + 1];
    pA += __shfl_xor(pA, 16, 64); pA += __shfl_xor(pA, 32, 64);
    pB += __shfl_xor(pB, 16, 64); pB += __shfl_xor(pB, 32, 64);
    if (lane < 16) { pred[0][w][lane] = pA; pred[1][w][lane] = pB; }
    __syncthreads();
    if (tid < 32) {
        int ch = tid >> 4, m = tid & 15;
        float sum = bout[0];
        #pragma unroll
        for (int ww = 0; ww < 4; ++ww) sum += pred[ch][ww][m];
        out[(btA + ch) * 16 + m] = fast_sigmoid(sum);
    }
}

extern "C" void kernel_launch(void* const* d_in, const int* in_sizes, int n_in,
                              void* d_out, int out_size, void* d_ws, size_t ws_size,
                              hipStream_t stream) {
    const float* x    = (const float*)d_in[0];
    const float* Wemb = (const float*)d_in[1];
    const float* bemb = (const float*)d_in[2];
    const float* Wf   = (const float*)d_in[3];
    const float* bfv  = (const float*)d_in[4];
    const float* Wi   = (const float*)d_in[5];
    const float* biv  = (const float*)d_in[6];
    const float* Wc   = (const float*)d_in[7];
    const float* bcv  = (const float*)d_in[8];
    const float* Wo   = (const float*)d_in[9];
    const float* bov  = (const float*)d_in[10];
    const float* Wout = (const float*)d_in[11];
    const float* bout = (const float*)d_in[12];
    float* out = (float*)d_out;
    unsigned int* e_ws = (unsigned int*)d_ws;   // 16 MiB fragment-layout e

    hipLaunchKernelGGL(embed_mfma, dim3(128 * 32), dim3(64), 0, stream,
                       x, Wemb, bemb, e_ws);
    hipLaunchKernelGGL(lstm_rec, dim3(B_ / 32), dim3(256), 0, stream,
                       Wf, bfv, Wi, biv, Wc, bcv, Wo, bov, Wout, bout,
                       (const unsigned int*)e_ws, out);
}